// Round 4
// baseline (412.527 us; speedup 1.0000x reference)
//
#include <hip/hip_runtime.h>
#include <math.h>

#define B_ 2
#define T_ 50
#define P_ 5111
#define U_ 64
#define SC_ 10            // s-steps per out-chunk
#define CH_ 5             // number of out-chunks (CH_*SC_ == T_)
#define NQ_ 1278          // ceil(P_/4) XWT quad tasks
#define XWTB_ 254         // xwt producer blocks (2..255)
#define OUT_BASE_ 256
#define OUTB_ 200         // 20 p-chunks x 2 b x 5 s-chunks
#define GRID_ (OUT_BASE_ + OUTB_)
#define MAGIC_ 0x5EED1E55

typedef float v2f __attribute__((ext_vector_type(2)));

// quad_perm DPP: dest lane i (within quad) <- src lane sel[i]
#define QPERM(x, ctrl)                                                        \
  __int_as_float(__builtin_amdgcn_mov_dpp(__float_as_int(x), (ctrl), 0xf, 0xf, true))

// ---------------------------------------------------------------------------
// Device-scope flag handoff. Flags live in poisoned workspace: producers
// write a MAGIC value (no zero-init needed); a uniform poison fill cannot
// equal MAGIC across slots, and a (p~2^-32) collision gives a wrong-answer
// fail, never a hang. Producers: syncthreads (drains vmcnt) -> threadfence
// -> release store. Consumers: acquire load spin -> syncthreads.
// ---------------------------------------------------------------------------
__device__ __forceinline__ void wait_flag(const int* f) {
  while (__hip_atomic_load(f, __ATOMIC_ACQUIRE, __HIP_MEMORY_SCOPE_AGENT) != MAGIC_)
    __builtin_amdgcn_s_sleep(2);
}
__device__ __forceinline__ void set_flag(int* f) {
  __threadfence();
  __hip_atomic_store(f, MAGIC_, __ATOMIC_RELEASE, __HIP_MEMORY_SCOPE_AGENT);
}

union SMem {
  struct { float H[T_ + 1][64]; float W1s[64 * 50]; } lstm;   // 25.9 KB
  float xe[256];                                              // zx
  float xrow[4][128];                                         // xwt
  struct { float G[T_ * 50]; float W2s[50]; int tgt[T_]; } outr;
};

// ---------------------------------------------------------------------------
// LSTM role (blocks 0,1): waits on the 50 ZX flags for its b, runs the
// serial 50-step chain, writes G, publishes gflag[b].
// ---------------------------------------------------------------------------
__device__ __forceinline__ void lstm_role(
    int b, SMem& sm, const float* ZX, const float* Wr, const float* bl,
    const float* W1, float* G, const int* zxflag, int* gflag) {
  const int k   = threadIdx.x;
  const int g   = k & 3;
  const int u   = k >> 2;
  const int col = g * 64 + u;

  v2f w2[32];
#pragma unroll
  for (int i = 0; i < 32; ++i) {
    v2f t; t.x = Wr[(2 * i) * 256 + col]; t.y = Wr[(2 * i + 1) * 256 + col];
    w2[i] = t;
  }
  const float blv = bl[col];
  if (k < 64) sm.lstm.H[0][k] = 0.f;
  if (k < T_) wait_flag(&zxflag[b * T_ + k]);
  __syncthreads();

  float znext = ZX[(b * T_) * 256 + col];
  float c = 0.f;

  __builtin_amdgcn_s_setprio(1);
  for (int t = 0; t < T_; ++t) {
    const float zcur = znext;
    if (t + 1 < T_) znext = ZX[(b * T_ + t + 1) * 256 + col];
    const float4* h4 = (const float4*)&sm.lstm.H[t][0];
    v2f a0 = {0.f, 0.f}, a1 = {0.f, 0.f}, a2 = {0.f, 0.f}, a3 = {0.f, 0.f};
#pragma unroll
    for (int q = 0; q < 16; ++q) {
      const float4 hq = h4[q];
      v2f hlo; hlo.x = hq.x; hlo.y = hq.y;
      v2f hhi; hhi.x = hq.z; hhi.y = hq.w;
      if (q & 1) {
        a2 = __builtin_elementwise_fma(hlo, w2[2 * q], a2);
        a3 = __builtin_elementwise_fma(hhi, w2[2 * q + 1], a3);
      } else {
        a0 = __builtin_elementwise_fma(hlo, w2[2 * q], a0);
        a1 = __builtin_elementwise_fma(hhi, w2[2 * q + 1], a1);
      }
    }
    const v2f as = (a0 + a2) + (a1 + a3);
    const float z = as.x + as.y + zcur + blv;
    const bool isg2 = (g == 2);
    const float arg = isg2 ? (2.f * z) : (-z);
    const float e   = __expf(arg);
    const float v   = __fdividef(1.f, 1.f + e);
    const float res = isg2 ? fmaf(-2.f, v, 1.f) : v;
    const float v1 = QPERM(res, 177);
    const float v2 = QPERM(res, 78);
    const float v3 = QPERM(res, 27);
    const float ig = (g == 0) ? res : (g == 1) ? v1 : (g == 2) ? v2 : v3;
    const float fg = (g == 1) ? res : (g == 0) ? v1 : (g == 3) ? v2 : v3;
    const float gg = (g == 2) ? res : (g == 3) ? v1 : (g == 0) ? v2 : v3;
    const float og = (g == 3) ? res : (g == 2) ? v1 : (g == 1) ? v2 : v3;
    c = fmaf(fg, c, ig * gg);
    const float th = fmaf(-2.f, __fdividef(1.f, 1.f + __expf(2.f * c)), 1.f);
    if (g == 0) sm.lstm.H[t + 1][u] = og * th;
    __syncthreads();
  }
  __builtin_amdgcn_s_setprio(0);

  // W1 staging deferred off the serial path.
  for (int i = k; i < 64 * 50; i += 256) sm.lstm.W1s[i] = W1[i];
  __syncthreads();

  const v2f* W1_2 = (const v2f*)sm.lstm.W1s;
  v2f*       G_2  = (v2f*)G;
  for (int task = k; task < T_ * 25; task += 256) {
    const int t  = task / 25;
    const int jp = task % 25;
    const float* hrow = &sm.lstm.H[t + 1][0];
    v2f acc = {0.f, 0.f};
#pragma unroll
    for (int u2 = 0; u2 < 64; ++u2) {
      v2f hb; hb.x = hrow[u2]; hb.y = hrow[u2];
      acc = __builtin_elementwise_fma(hb, W1_2[u2 * 25 + jp], acc);
    }
    G_2[b * (T_ * 25) + task] = acc;
  }
  __syncthreads();
  if (k == 0) set_flag(&gflag[b]);
}

// ---------------------------------------------------------------------------
// Producer role (blocks 2..255): blocks 2..101 first do their ZX task
// (bt = blk-2) and flag it; then all 254 blocks stripe the 1278 XWT quads
// (blocks 102.. own the first stripes so the zx blocks' late start lands on
// the last stripes). Each quad is flagged individually for fine-grained
// consumption by the out role.
// ---------------------------------------------------------------------------
__device__ __forceinline__ void prod_role(
    int blk, SMem& sm, const int* tgt, const int* cor, const float* X,
    const float* emb2, const float* Wk, const float* W1, const float* b1,
    float* ZX, float* XWT, int* zxflag, int* quadflag) {
  const int k = threadIdx.x;

  if (blk - 2 < B_ * T_) {
    const int bt = blk - 2;
    const int t_ = tgt[bt], c_ = cor[bt];
    sm.xe[k] = X[t_ * 128 + (k & 127)] * emb2[c_ * 256 + k];
    __syncthreads();
    float z = 0.f;
#pragma unroll 8
    for (int d = 0; d < 256; ++d)
      z = fmaf(sm.xe[d], Wk[d * 256 + k], z);
    ZX[bt * 256 + k] = z;
    __syncthreads();   // drains ZX stores of all waves; xe dead after this
    if (k == 0) set_flag(&zxflag[bt]);
  }

  const int sub = k >> 6, lane = k & 63;
  const int stripe = (blk - 102 + XWTB_) % XWTB_;
  for (int q = stripe; q < NQ_; q += XWTB_) {
    const int p = q * 4 + sub;
    if (p < P_) {
      sm.xrow[sub][lane]      = X[p * 128 + lane];
      sm.xrow[sub][64 + lane] = X[p * 128 + 64 + lane];
    }
    __syncthreads();
    if (p < P_ && lane < 50) {
      float acc = b1[lane];
#pragma unroll 16
      for (int u = 0; u < 128; ++u)
        acc = fmaf(sm.xrow[sub][u], W1[(64 + u) * 50 + lane], acc);
      XWT[lane * P_ + p] = acc;
    }
    __syncthreads();   // drains XWT stores of all waves
    if (k == 0) set_flag(&quadflag[q]);
  }
}

// ---------------------------------------------------------------------------
// Out role (blocks 256..455): stage tgt/W2, issue ALL cosX gathers (no deps),
// wait per-quad XWT flags for this p-chunk, load S2, wait gflag[b], load G,
// compute. Accumulation order identical to the verified kernel.
// ---------------------------------------------------------------------------
template <int CH>
__device__ __forceinline__ void out_body(
    int pc, int b, SMem& sm, const int* tgt, const float* cosX,
    const float* G, const float* XWT, const float* W2, const float* b2,
    float* out, const int* gflag, const int* quadflag) {
  constexpr int s_lo = CH * SC_;
  constexpr int s_hi = s_lo + SC_;
  const int tid = threadIdx.x;
  const int p   = pc * 256 + tid;
  const bool act = (p < P_);

  if (tid < 50) {
    sm.outr.W2s[tid] = W2[tid];
    sm.outr.tgt[tid] = tgt[b * T_ + tid];
  }
  __syncthreads();

  // cosX gathers: no dependency on any producer -> issue first.
  float av[T_ - s_lo];
#pragma unroll
  for (int t = s_lo; t < T_; ++t)
    av[t - s_lo] = act ? cosX[sm.outr.tgt[t] * P_ + p] : 0.f;

  // Wait for the 64 XWT quads covering this p-chunk.
  if (tid < 64) {
    const int q = pc * 64 + tid;
    if (q < NQ_) wait_flag(&quadflag[q]);
  }
  __syncthreads();

  v2f S2[25];
#pragma unroll
  for (int jj = 0; jj < 25; ++jj) {
    v2f t2;
    t2.x = act ? XWT[(2 * jj) * P_ + p] : 0.f;
    t2.y = act ? XWT[(2 * jj + 1) * P_ + p] : 0.f;
    S2[jj] = t2;
  }

  if (tid == 0) wait_flag(&gflag[b]);
  __syncthreads();
  for (int i = s_lo * 50 + tid; i < T_ * 50; i += 256)
    sm.outr.G[i] = G[b * T_ * 50 + i];
  __syncthreads();

  // Suffix prefix: t = T-1 down to s_hi — same fma order as verified kernel.
#pragma unroll
  for (int t = T_ - 1; t >= s_hi; --t) {
    const v2f* G2 = (const v2f*)&sm.outr.G[t * 50];
    v2f av2; av2.x = av[t - s_lo]; av2.y = av[t - s_lo];
#pragma unroll
    for (int jj = 0; jj < 25; ++jj)
      S2[jj] = __builtin_elementwise_fma(av2, G2[jj], S2[jj]);
  }

  const v2f* W2_2 = (const v2f*)sm.outr.W2s;
  const float b2v = b2[0];
  const v2f zero2 = {0.f, 0.f};
#pragma unroll
  for (int s = s_hi - 1; s >= s_lo; --s) {
    const v2f* G2 = (const v2f*)&sm.outr.G[s * 50];
    v2f av2; av2.x = av[s - s_lo]; av2.y = av[s - s_lo];
    v2f acc2; acc2.x = b2v; acc2.y = 0.f;
#pragma unroll
    for (int jj = 0; jj < 25; ++jj) {
      S2[jj] = __builtin_elementwise_fma(av2, G2[jj], S2[jj]);
      const v2f r = __builtin_elementwise_max(S2[jj], zero2);
      acc2 = __builtin_elementwise_fma(r, W2_2[jj], acc2);
    }
    if (act) out[(b * T_ + s) * P_ + p] = acc2.x + acc2.y;
  }
}

// ---------------------------------------------------------------------------
// Single fused kernel: 456 blocks, all co-resident (<=2 blocks/CU, 26 KB LDS,
// 4 waves/block). No barriers are divergent; every awaited flag has an
// unconditional producer among co-resident blocks -> deadlock-free.
// ---------------------------------------------------------------------------
__global__ __launch_bounds__(256) void mega_kernel(
    const int* __restrict__ tgt, const int* __restrict__ cor,
    const float* __restrict__ X, const float* __restrict__ cosX,
    const float* __restrict__ emb2, const float* __restrict__ Wk,
    const float* __restrict__ Wr, const float* __restrict__ bl,
    const float* __restrict__ W1, const float* __restrict__ b1,
    const float* __restrict__ W2, const float* __restrict__ b2,
    float* __restrict__ ZX, float* __restrict__ G, float* __restrict__ XWT,
    int* __restrict__ zxflag, int* __restrict__ gflag,
    int* __restrict__ quadflag, float* __restrict__ out) {
  __shared__ __align__(16) SMem sm;
  const int blk = blockIdx.x;

  if (blk < B_) {
    lstm_role(blk, sm, ZX, Wr, bl, W1, G, zxflag, gflag);
    return;
  }
  if (blk < OUT_BASE_) {
    prod_role(blk, sm, tgt, cor, X, emb2, Wk, W1, b1, ZX, XWT, zxflag, quadflag);
    return;
  }
  const int obi = blk - OUT_BASE_;
  const int pc  = obi % 20;
  const int b   = (obi / 20) & 1;
  switch (obi / 40) {
    case 0: out_body<0>(pc, b, sm, tgt, cosX, G, XWT, W2, b2, out, gflag, quadflag); break;
    case 1: out_body<1>(pc, b, sm, tgt, cosX, G, XWT, W2, b2, out, gflag, quadflag); break;
    case 2: out_body<2>(pc, b, sm, tgt, cosX, G, XWT, W2, b2, out, gflag, quadflag); break;
    case 3: out_body<3>(pc, b, sm, tgt, cosX, G, XWT, W2, b2, out, gflag, quadflag); break;
    default: out_body<4>(pc, b, sm, tgt, cosX, G, XWT, W2, b2, out, gflag, quadflag); break;
  }
}

extern "C" void kernel_launch(void* const* d_in, const int* in_sizes, int n_in,
                              void* d_out, int out_size, void* d_ws, size_t ws_size,
                              hipStream_t stream) {
  const int*   tgt  = (const int*)d_in[0];
  const int*   cor  = (const int*)d_in[1];
  const float* X    = (const float*)d_in[3];
  const float* cosX = (const float*)d_in[4];
  const float* emb2 = (const float*)d_in[6];
  const float* Wk   = (const float*)d_in[7];
  const float* Wr   = (const float*)d_in[8];
  const float* bl   = (const float*)d_in[9];
  const float* W1   = (const float*)d_in[10];
  const float* b1   = (const float*)d_in[11];
  const float* W2   = (const float*)d_in[12];
  const float* b2   = (const float*)d_in[13];
  float* out = (float*)d_out;

  float* ws  = (float*)d_ws;
  float* ZX  = ws;            // 100*256 = 25600 floats
  float* G   = ws + 25600;    // 100*50  =  5000 floats
  float* XWT = ws + 30600;    // 50*5111 = 255550 floats
  int*   fl  = (int*)(ws + 286150);
  int* zxflag   = fl;         // 100
  int* gflag    = fl + 100;   // 2
  int* quadflag = fl + 102;   // 1278

  mega_kernel<<<dim3(GRID_), dim3(256), 0, stream>>>(
      tgt, cor, X, cosX, emb2, Wk, Wr, bl, W1, b1, W2, b2,
      ZX, G, XWT, zxflag, gflag, quadflag, out);
}

// Round 5
// 219.998 us; speedup vs baseline: 1.8751x; 1.8751x over previous
//
#include <hip/hip_runtime.h>
#include <math.h>

#define B_ 2
#define T_ 50
#define P_ 5111
#define U_ 64
#define SC_ 10            // s-steps per out-chunk
#define CH_ 5             // number of out-chunks (CH_*SC_ == T_)
#define NQ_ 1278          // ceil(P_/4) XWT quad tasks
#define XWTB_ 254         // xwt producer blocks (2..255)
#define OUT_BASE_ 256
#define OUTB_ 200         // 20 p-chunks x 2 b x 5 s-chunks
#define GRID_ (OUT_BASE_ + OUTB_)
#define MAGIC_ 0x5EED1E55

typedef float v2f __attribute__((ext_vector_type(2)));

// quad_perm DPP: dest lane i (within quad) <- src lane sel[i]
#define QPERM(x, ctrl)                                                        \
  __int_as_float(__builtin_amdgcn_mov_dpp(__float_as_int(x), (ctrl), 0xf, 0xf, true))

// ---------------------------------------------------------------------------
// LLC-coherent handoff primitives. RELAXED + AGENT scope lowers to plain
// global_load/store with sc1 (bypass the non-coherent per-XCD L2s, hit the
// device-coherent LLC). NO buffer_inv / buffer_wbl2 is ever emitted — that
// cache-maintenance storm was round-4's 273 us. Ordering discipline:
//   producer: st_coh data -> __syncthreads (per-wave vmcnt(0) drain) -> flag
//   consumer: spin on flag -> __syncthreads (compiler+convergence barrier)
//             -> ld_coh data
// Flags are magic-valued in poisoned workspace: no init needed; a collision
// is a wrong-answer fail (p~2^-32), never a hang.
// ---------------------------------------------------------------------------
__device__ __forceinline__ float ld_coh(const float* p) {
  return __hip_atomic_load(p, __ATOMIC_RELAXED, __HIP_MEMORY_SCOPE_AGENT);
}
__device__ __forceinline__ void st_coh(float* p, float v) {
  __hip_atomic_store(p, v, __ATOMIC_RELAXED, __HIP_MEMORY_SCOPE_AGENT);
}
__device__ __forceinline__ void wait_flag(const int* f) {
  while (__hip_atomic_load(f, __ATOMIC_RELAXED, __HIP_MEMORY_SCOPE_AGENT) != MAGIC_)
    __builtin_amdgcn_s_sleep(2);
}
__device__ __forceinline__ void set_flag(int* f) {
  __hip_atomic_store(f, MAGIC_, __ATOMIC_RELAXED, __HIP_MEMORY_SCOPE_AGENT);
}

union SMem {
  struct { float H[T_ + 1][64]; float W1s[64 * 50]; } lstm;   // 25.9 KB
  float xe[256];                                              // zx
  float xrow[4][128];                                         // xwt
  struct { float G[T_ * 50]; float W2s[50]; int tgt[T_]; } outr;
};

// ---------------------------------------------------------------------------
// LSTM role (blocks 0,1): waits on the 50 ZX flags for its b, runs the
// serial 50-step chain (ZX prefetch depth 3 to cover ~600cy LLC latency),
// writes G, publishes gflag[b].
// ---------------------------------------------------------------------------
__device__ __forceinline__ void lstm_role(
    int b, SMem& sm, const float* ZX, const float* Wr, const float* bl,
    const float* W1, float* G, const int* zxflag, int* gflag) {
  const int k   = threadIdx.x;
  const int g   = k & 3;
  const int u   = k >> 2;
  const int col = g * 64 + u;

  v2f w2[32];
#pragma unroll
  for (int i = 0; i < 32; ++i) {
    v2f t; t.x = Wr[(2 * i) * 256 + col]; t.y = Wr[(2 * i + 1) * 256 + col];
    w2[i] = t;
  }
  const float blv = bl[col];
  if (k < 64) sm.lstm.H[0][k] = 0.f;
  if (k < T_) wait_flag(&zxflag[b * T_ + k]);
  __syncthreads();

  // ZX prefetch pipeline, depth 3 (LLC ~600cy > one chain step ~250cy).
  float zn0 = ld_coh(&ZX[(b * T_ + 0) * 256 + col]);
  float zn1 = ld_coh(&ZX[(b * T_ + 1) * 256 + col]);
  float zn2 = ld_coh(&ZX[(b * T_ + 2) * 256 + col]);
  float c = 0.f;

  __builtin_amdgcn_s_setprio(1);
  for (int t = 0; t < T_; ++t) {
    const float zcur = zn0;
    zn0 = zn1; zn1 = zn2;
    if (t + 3 < T_) zn2 = ld_coh(&ZX[(b * T_ + t + 3) * 256 + col]);
    const float4* h4 = (const float4*)&sm.lstm.H[t][0];
    v2f a0 = {0.f, 0.f}, a1 = {0.f, 0.f}, a2 = {0.f, 0.f}, a3 = {0.f, 0.f};
#pragma unroll
    for (int q = 0; q < 16; ++q) {
      const float4 hq = h4[q];
      v2f hlo; hlo.x = hq.x; hlo.y = hq.y;
      v2f hhi; hhi.x = hq.z; hhi.y = hq.w;
      if (q & 1) {
        a2 = __builtin_elementwise_fma(hlo, w2[2 * q], a2);
        a3 = __builtin_elementwise_fma(hhi, w2[2 * q + 1], a3);
      } else {
        a0 = __builtin_elementwise_fma(hlo, w2[2 * q], a0);
        a1 = __builtin_elementwise_fma(hhi, w2[2 * q + 1], a1);
      }
    }
    const v2f as = (a0 + a2) + (a1 + a3);
    const float z = as.x + as.y + zcur + blv;
    const bool isg2 = (g == 2);
    const float arg = isg2 ? (2.f * z) : (-z);
    const float e   = __expf(arg);
    const float v   = __fdividef(1.f, 1.f + e);
    const float res = isg2 ? fmaf(-2.f, v, 1.f) : v;
    const float v1 = QPERM(res, 177);
    const float v2 = QPERM(res, 78);
    const float v3 = QPERM(res, 27);
    const float ig = (g == 0) ? res : (g == 1) ? v1 : (g == 2) ? v2 : v3;
    const float fg = (g == 1) ? res : (g == 0) ? v1 : (g == 3) ? v2 : v3;
    const float gg = (g == 2) ? res : (g == 3) ? v1 : (g == 0) ? v2 : v3;
    const float og = (g == 3) ? res : (g == 2) ? v1 : (g == 1) ? v2 : v3;
    c = fmaf(fg, c, ig * gg);
    const float th = fmaf(-2.f, __fdividef(1.f, 1.f + __expf(2.f * c)), 1.f);
    if (g == 0) sm.lstm.H[t + 1][u] = og * th;
    __syncthreads();
  }
  __builtin_amdgcn_s_setprio(0);

  // W1 staging deferred off the serial path.
  for (int i = k; i < 64 * 50; i += 256) sm.lstm.W1s[i] = W1[i];
  __syncthreads();

  const v2f* W1_2 = (const v2f*)sm.lstm.W1s;
  for (int task = k; task < T_ * 25; task += 256) {
    const int t  = task / 25;
    const int jp = task % 25;
    const float* hrow = &sm.lstm.H[t + 1][0];
    v2f acc = {0.f, 0.f};
#pragma unroll
    for (int u2 = 0; u2 < 64; ++u2) {
      v2f hb; hb.x = hrow[u2]; hb.y = hrow[u2];
      acc = __builtin_elementwise_fma(hb, W1_2[u2 * 25 + jp], acc);
    }
    st_coh(&G[b * (T_ * 50) + 2 * task],     acc.x);
    st_coh(&G[b * (T_ * 50) + 2 * task + 1], acc.y);
  }
  __syncthreads();
  if (k == 0) set_flag(&gflag[b]);
}

// ---------------------------------------------------------------------------
// Producer role (blocks 2..255): blocks 2..101 first do their ZX task
// (bt = blk-2) and flag it; then all 254 blocks stripe the 1278 XWT quads
// (blocks 102.. own the first stripes, so low quads — consumed first by the
// out role — are produced in the first pass). Per-quad flags.
// ---------------------------------------------------------------------------
__device__ __forceinline__ void prod_role(
    int blk, SMem& sm, const int* tgt, const int* cor, const float* X,
    const float* emb2, const float* Wk, const float* W1, const float* b1,
    float* ZX, float* XWT, int* zxflag, int* quadflag) {
  const int k = threadIdx.x;

  if (blk - 2 < B_ * T_) {
    const int bt = blk - 2;
    const int t_ = tgt[bt], c_ = cor[bt];
    sm.xe[k] = X[t_ * 128 + (k & 127)] * emb2[c_ * 256 + k];
    __syncthreads();
    float z = 0.f;
#pragma unroll 8
    for (int d = 0; d < 256; ++d)
      z = fmaf(sm.xe[d], Wk[d * 256 + k], z);
    st_coh(&ZX[bt * 256 + k], z);
    __syncthreads();   // all waves at vmcnt(0): ZX visible at LLC
    if (k == 0) set_flag(&zxflag[bt]);
  }

  const int sub = k >> 6, lane = k & 63;
  const int stripe = (blk - 102 + XWTB_) % XWTB_;
  for (int q = stripe; q < NQ_; q += XWTB_) {
    const int p = q * 4 + sub;
    if (p < P_) {
      sm.xrow[sub][lane]      = X[p * 128 + lane];
      sm.xrow[sub][64 + lane] = X[p * 128 + 64 + lane];
    }
    __syncthreads();
    if (p < P_ && lane < 50) {
      float acc = b1[lane];
#pragma unroll 16
      for (int u = 0; u < 128; ++u)
        acc = fmaf(sm.xrow[sub][u], W1[(64 + u) * 50 + lane], acc);
      st_coh(&XWT[lane * P_ + p], acc);
    }
    __syncthreads();   // all waves at vmcnt(0): this quad visible at LLC
    if (k == 0) set_flag(&quadflag[q]);
  }
}

// ---------------------------------------------------------------------------
// Out role (blocks 256..455): stage tgt/W2, issue ALL cosX gathers (inputs,
// no deps), wait per-quad XWT flags for this p-chunk, load S2 (sc1), wait
// gflag[b], load G (sc1), compute. Accumulation order identical to the
// verified kernel.
// ---------------------------------------------------------------------------
template <int CH>
__device__ __forceinline__ void out_body(
    int pc, int b, SMem& sm, const int* tgt, const float* cosX,
    const float* G, const float* XWT, const float* W2, const float* b2,
    float* out, const int* gflag, const int* quadflag) {
  constexpr int s_lo = CH * SC_;
  constexpr int s_hi = s_lo + SC_;
  const int tid = threadIdx.x;
  const int p   = pc * 256 + tid;
  const bool act = (p < P_);

  if (tid < 50) {
    sm.outr.W2s[tid] = W2[tid];
    sm.outr.tgt[tid] = tgt[b * T_ + tid];
  }
  __syncthreads();

  // cosX gathers: input data, no producer dependency -> issue first.
  float av[T_ - s_lo];
#pragma unroll
  for (int t = s_lo; t < T_; ++t)
    av[t - s_lo] = act ? cosX[sm.outr.tgt[t] * P_ + p] : 0.f;

  // Wait for the 64 XWT quads covering this p-chunk.
  if (tid < 64) {
    const int q = pc * 64 + tid;
    if (q < NQ_) wait_flag(&quadflag[q]);
  }
  __syncthreads();

  v2f S2[25];
#pragma unroll
  for (int jj = 0; jj < 25; ++jj) {
    v2f t2;
    t2.x = act ? ld_coh(&XWT[(2 * jj) * P_ + p]) : 0.f;
    t2.y = act ? ld_coh(&XWT[(2 * jj + 1) * P_ + p]) : 0.f;
    S2[jj] = t2;
  }

  if (tid == 0) wait_flag(&gflag[b]);
  __syncthreads();
  for (int i = s_lo * 50 + tid; i < T_ * 50; i += 256)
    sm.outr.G[i] = ld_coh(&G[b * T_ * 50 + i]);
  __syncthreads();

  // Suffix prefix: t = T-1 down to s_hi — same fma order as verified kernel.
#pragma unroll
  for (int t = T_ - 1; t >= s_hi; --t) {
    const v2f* G2 = (const v2f*)&sm.outr.G[t * 50];
    v2f av2; av2.x = av[t - s_lo]; av2.y = av[t - s_lo];
#pragma unroll
    for (int jj = 0; jj < 25; ++jj)
      S2[jj] = __builtin_elementwise_fma(av2, G2[jj], S2[jj]);
  }

  const v2f* W2_2 = (const v2f*)sm.outr.W2s;
  const float b2v = b2[0];
  const v2f zero2 = {0.f, 0.f};
#pragma unroll
  for (int s = s_hi - 1; s >= s_lo; --s) {
    const v2f* G2 = (const v2f*)&sm.outr.G[s * 50];
    v2f av2; av2.x = av[s - s_lo]; av2.y = av[s - s_lo];
    v2f acc2; acc2.x = b2v; acc2.y = 0.f;
#pragma unroll
    for (int jj = 0; jj < 25; ++jj) {
      S2[jj] = __builtin_elementwise_fma(av2, G2[jj], S2[jj]);
      const v2f r = __builtin_elementwise_max(S2[jj], zero2);
      acc2 = __builtin_elementwise_fma(r, W2_2[jj], acc2);
    }
    if (act) out[(b * T_ + s) * P_ + p] = acc2.x + acc2.y;
  }
}

// ---------------------------------------------------------------------------
// Single fused kernel: 456 blocks, all co-resident (26 KB LDS, 4 waves/block
// -> >=2 blocks/CU, 512 slots >= 456: deadlock-free regardless of dispatch
// order). Every awaited flag has an unconditional producer.
// ---------------------------------------------------------------------------
__global__ __launch_bounds__(256) void mega_kernel(
    const int* __restrict__ tgt, const int* __restrict__ cor,
    const float* __restrict__ X, const float* __restrict__ cosX,
    const float* __restrict__ emb2, const float* __restrict__ Wk,
    const float* __restrict__ Wr, const float* __restrict__ bl,
    const float* __restrict__ W1, const float* __restrict__ b1,
    const float* __restrict__ W2, const float* __restrict__ b2,
    float* __restrict__ ZX, float* __restrict__ G, float* __restrict__ XWT,
    int* __restrict__ zxflag, int* __restrict__ gflag,
    int* __restrict__ quadflag, float* __restrict__ out) {
  __shared__ __align__(16) SMem sm;
  const int blk = blockIdx.x;

  if (blk < B_) {
    lstm_role(blk, sm, ZX, Wr, bl, W1, G, zxflag, gflag);
    return;
  }
  if (blk < OUT_BASE_) {
    prod_role(blk, sm, tgt, cor, X, emb2, Wk, W1, b1, ZX, XWT, zxflag, quadflag);
    return;
  }
  const int obi = blk - OUT_BASE_;
  const int pc  = obi % 20;
  const int b   = (obi / 20) & 1;
  switch (obi / 40) {
    case 0: out_body<0>(pc, b, sm, tgt, cosX, G, XWT, W2, b2, out, gflag, quadflag); break;
    case 1: out_body<1>(pc, b, sm, tgt, cosX, G, XWT, W2, b2, out, gflag, quadflag); break;
    case 2: out_body<2>(pc, b, sm, tgt, cosX, G, XWT, W2, b2, out, gflag, quadflag); break;
    case 3: out_body<3>(pc, b, sm, tgt, cosX, G, XWT, W2, b2, out, gflag, quadflag); break;
    default: out_body<4>(pc, b, sm, tgt, cosX, G, XWT, W2, b2, out, gflag, quadflag); break;
  }
}

extern "C" void kernel_launch(void* const* d_in, const int* in_sizes, int n_in,
                              void* d_out, int out_size, void* d_ws, size_t ws_size,
                              hipStream_t stream) {
  const int*   tgt  = (const int*)d_in[0];
  const int*   cor  = (const int*)d_in[1];
  const float* X    = (const float*)d_in[3];
  const float* cosX = (const float*)d_in[4];
  const float* emb2 = (const float*)d_in[6];
  const float* Wk   = (const float*)d_in[7];
  const float* Wr   = (const float*)d_in[8];
  const float* bl   = (const float*)d_in[9];
  const float* W1   = (const float*)d_in[10];
  const float* b1   = (const float*)d_in[11];
  const float* W2   = (const float*)d_in[12];
  const float* b2   = (const float*)d_in[13];
  float* out = (float*)d_out;

  float* ws  = (float*)d_ws;
  float* ZX  = ws;            // 100*256 = 25600 floats
  float* G   = ws + 25600;    // 100*50  =  5000 floats
  float* XWT = ws + 30600;    // 50*5111 = 255550 floats
  int*   fl  = (int*)(ws + 286150);
  int* zxflag   = fl;         // 100
  int* gflag    = fl + 100;   // 2
  int* quadflag = fl + 102;   // 1278

  mega_kernel<<<dim3(GRID_), dim3(256), 0, stream>>>(
      tgt, cor, X, cosX, emb2, Wk, Wr, bl, W1, b1, W2, b2,
      ZX, G, XWT, zxflag, gflag, quadflag, out);
}

// Round 6
// 216.307 us; speedup vs baseline: 1.9071x; 1.0171x over previous
//
#include <hip/hip_runtime.h>
#include <math.h>

#define B_ 2
#define T_ 50
#define P_ 5111
#define U_ 64
#define SC_ 10            // s-steps per out-chunk
#define CH_ 5             // number of out-chunks (CH_*SC_ == T_)
#define NQ_ 1278          // ceil(P_/4) XWT quad tasks
#define XWTB_ 254         // xwt producer blocks (2..255)
#define OUT_BASE_ 256
#define OUTB_ 200         // 20 p-chunks x 2 b x 5 s-chunks
#define GRID_ (OUT_BASE_ + OUTB_)
#define MAGIC_ 0x5EED1E55

typedef float v2f __attribute__((ext_vector_type(2)));

// quad_perm DPP: dest lane i (within quad) <- src lane sel[i]
#define QPERM(x, ctrl)                                                        \
  __int_as_float(__builtin_amdgcn_mov_dpp(__float_as_int(x), (ctrl), 0xf, 0xf, true))

// ---------------------------------------------------------------------------
// LLC-coherent handoff primitives (RELAXED+AGENT -> plain sc1 loads/stores,
// no buffer_inv/wbl2 cache maintenance). Ordering:
//   producer: st_coh data -> __syncthreads (vmcnt(0) drain) -> set_flag
//   consumer: wait_flag -> __syncthreads -> ld_coh data
// Flags are magic-valued in poisoned workspace (no init; collision = wrong
// answer at p~2^-32, never a hang).
// ---------------------------------------------------------------------------
__device__ __forceinline__ float ld_coh(const float* p) {
  return __hip_atomic_load(p, __ATOMIC_RELAXED, __HIP_MEMORY_SCOPE_AGENT);
}
__device__ __forceinline__ void st_coh(float* p, float v) {
  __hip_atomic_store(p, v, __ATOMIC_RELAXED, __HIP_MEMORY_SCOPE_AGENT);
}
__device__ __forceinline__ void wait_flag(const int* f) {
  while (__hip_atomic_load(f, __ATOMIC_RELAXED, __HIP_MEMORY_SCOPE_AGENT) != MAGIC_)
    __builtin_amdgcn_s_sleep(2);
}
__device__ __forceinline__ void set_flag(int* f) {
  __hip_atomic_store(f, MAGIC_, __ATOMIC_RELAXED, __HIP_MEMORY_SCOPE_AGENT);
}

union SMem {
  struct {
    float H[T_ + 1][64];                       // 13056 B
    union {
      float ZXs[T_][256];                      // 51200 B (live during t-loop)
      float W1s[64 * 50];                      // 12800 B (live in epilogue)
    } z;
  } lstm;                                      // 64256 B total
  float xe[256];                               // zx
  float xrow[4][128];                          // xwt
  struct { float G[T_ * 50]; float W2s[50]; int tgt[T_]; } outr;
};

// ---------------------------------------------------------------------------
// LSTM role (blocks 0,1). Key change vs round 5: the 50-step serial loop is
// GLOBAL-LOAD-FREE. All ZX for this b is bulk-staged into LDS up front (one
// vmcnt drain instead of one exposed LLC round-trip per step — the per-step
// __syncthreads drains vmcnt(0), so any in-loop global load serializes the
// chain on LLC latency). W1 epilogue data is pre-loaded into registers under
// the same drain.
// ---------------------------------------------------------------------------
__device__ __forceinline__ void lstm_role(
    int b, SMem& sm, const float* ZX, const float* Wr, const float* bl,
    const float* W1, float* G, const int* zxflag, int* gflag) {
  const int k   = threadIdx.x;
  const int g   = k & 3;
  const int u   = k >> 2;
  const int col = g * 64 + u;

  v2f w2[32];
#pragma unroll
  for (int i = 0; i < 32; ++i) {
    v2f t; t.x = Wr[(2 * i) * 256 + col]; t.y = Wr[(2 * i + 1) * 256 + col];
    w2[i] = t;
  }
  const float blv = bl[col];
  if (k < 64) sm.lstm.H[0][k] = 0.f;
  if (k < T_) wait_flag(&zxflag[b * T_ + k]);
  __syncthreads();

  // Bulk ZX -> LDS stage: thread k stages element k of every row t.
  // Coalesced sc1 loads, conflict-free ds_writes, all in flight together.
  {
    float r[T_];
#pragma unroll
    for (int t = 0; t < T_; ++t) r[t] = ld_coh(&ZX[(b * T_ + t) * 256 + k]);
#pragma unroll
    for (int t = 0; t < T_; ++t) sm.lstm.z.ZXs[t][k] = r[t];
  }
  // W1 epilogue data pre-loaded into registers (drained by the same barrier).
  float w1r[13];
#pragma unroll
  for (int j = 0; j < 13; ++j) {
    const int i = k + j * 256;
    w1r[j] = (i < 64 * 50) ? W1[i] : 0.f;
  }
  __syncthreads();

  float c = 0.f;
  __builtin_amdgcn_s_setprio(1);
  for (int t = 0; t < T_; ++t) {
    const float zcur = sm.lstm.z.ZXs[t][col];   // LDS, no vmcnt
    const float4* h4 = (const float4*)&sm.lstm.H[t][0];
    v2f a0 = {0.f, 0.f}, a1 = {0.f, 0.f}, a2 = {0.f, 0.f}, a3 = {0.f, 0.f};
#pragma unroll
    for (int q = 0; q < 16; ++q) {
      const float4 hq = h4[q];
      v2f hlo; hlo.x = hq.x; hlo.y = hq.y;
      v2f hhi; hhi.x = hq.z; hhi.y = hq.w;
      if (q & 1) {
        a2 = __builtin_elementwise_fma(hlo, w2[2 * q], a2);
        a3 = __builtin_elementwise_fma(hhi, w2[2 * q + 1], a3);
      } else {
        a0 = __builtin_elementwise_fma(hlo, w2[2 * q], a0);
        a1 = __builtin_elementwise_fma(hhi, w2[2 * q + 1], a1);
      }
    }
    const v2f as = (a0 + a2) + (a1 + a3);
    const float z = as.x + as.y + zcur + blv;
    const bool isg2 = (g == 2);
    const float arg = isg2 ? (2.f * z) : (-z);
    const float e   = __expf(arg);
    const float v   = __fdividef(1.f, 1.f + e);
    const float res = isg2 ? fmaf(-2.f, v, 1.f) : v;
    const float v1 = QPERM(res, 177);
    const float v2 = QPERM(res, 78);
    const float v3 = QPERM(res, 27);
    const float ig = (g == 0) ? res : (g == 1) ? v1 : (g == 2) ? v2 : v3;
    const float fg = (g == 1) ? res : (g == 0) ? v1 : (g == 3) ? v2 : v3;
    const float gg = (g == 2) ? res : (g == 3) ? v1 : (g == 0) ? v2 : v3;
    const float og = (g == 3) ? res : (g == 2) ? v1 : (g == 1) ? v2 : v3;
    c = fmaf(fg, c, ig * gg);
    const float th = fmaf(-2.f, __fdividef(1.f, 1.f + __expf(2.f * c)), 1.f);
    if (g == 0) sm.lstm.H[t + 1][u] = og * th;
    __syncthreads();
  }
  __builtin_amdgcn_s_setprio(0);

  // Epilogue: W1s overlays the (now dead) ZXs region; data already in regs.
#pragma unroll
  for (int j = 0; j < 13; ++j) {
    const int i = k + j * 256;
    if (i < 64 * 50) sm.lstm.z.W1s[i] = w1r[j];
  }
  __syncthreads();

  const v2f* W1_2 = (const v2f*)sm.lstm.z.W1s;
  for (int task = k; task < T_ * 25; task += 256) {
    const int t  = task / 25;
    const int jp = task % 25;
    const float* hrow = &sm.lstm.H[t + 1][0];
    v2f acc = {0.f, 0.f};
#pragma unroll
    for (int u2 = 0; u2 < 64; ++u2) {
      v2f hb; hb.x = hrow[u2]; hb.y = hrow[u2];
      acc = __builtin_elementwise_fma(hb, W1_2[u2 * 25 + jp], acc);
    }
    st_coh(&G[b * (T_ * 50) + 2 * task],     acc.x);
    st_coh(&G[b * (T_ * 50) + 2 * task + 1], acc.y);
  }
  __syncthreads();
  if (k == 0) set_flag(&gflag[b]);
}

// ---------------------------------------------------------------------------
// Producer role (blocks 2..255): blocks 2..101 do their ZX task first and
// flag it; then all 254 blocks stripe the 1278 XWT quads (blocks 102.. own
// the first stripes so low quads are produced first). Per-quad flags.
// ---------------------------------------------------------------------------
__device__ __forceinline__ void prod_role(
    int blk, SMem& sm, const int* tgt, const int* cor, const float* X,
    const float* emb2, const float* Wk, const float* W1, const float* b1,
    float* ZX, float* XWT, int* zxflag, int* quadflag) {
  const int k = threadIdx.x;

  if (blk - 2 < B_ * T_) {
    const int bt = blk - 2;
    const int t_ = tgt[bt], c_ = cor[bt];
    sm.xe[k] = X[t_ * 128 + (k & 127)] * emb2[c_ * 256 + k];
    __syncthreads();
    float z = 0.f;
#pragma unroll 8
    for (int d = 0; d < 256; ++d)
      z = fmaf(sm.xe[d], Wk[d * 256 + k], z);
    st_coh(&ZX[bt * 256 + k], z);
    __syncthreads();   // all waves at vmcnt(0): ZX visible at LLC
    if (k == 0) set_flag(&zxflag[bt]);
  }

  const int sub = k >> 6, lane = k & 63;
  const int stripe = (blk - 102 + XWTB_) % XWTB_;
  for (int q = stripe; q < NQ_; q += XWTB_) {
    const int p = q * 4 + sub;
    if (p < P_) {
      sm.xrow[sub][lane]      = X[p * 128 + lane];
      sm.xrow[sub][64 + lane] = X[p * 128 + 64 + lane];
    }
    __syncthreads();
    if (p < P_ && lane < 50) {
      float acc = b1[lane];
#pragma unroll 16
      for (int u = 0; u < 128; ++u)
        acc = fmaf(sm.xrow[sub][u], W1[(64 + u) * 50 + lane], acc);
      st_coh(&XWT[lane * P_ + p], acc);
    }
    __syncthreads();   // all waves at vmcnt(0): this quad visible at LLC
    if (k == 0) set_flag(&quadflag[q]);
  }
}

// ---------------------------------------------------------------------------
// Out role (blocks 256..455): stage tgt/W2, issue ALL cosX gathers (inputs,
// no deps), wait per-quad XWT flags for this p-chunk, load S2 (sc1), wait
// gflag[b], load G (sc1), compute. Accumulation order identical to the
// verified kernel.
// ---------------------------------------------------------------------------
template <int CH>
__device__ __forceinline__ void out_body(
    int pc, int b, SMem& sm, const int* tgt, const float* cosX,
    const float* G, const float* XWT, const float* W2, const float* b2,
    float* out, const int* gflag, const int* quadflag) {
  constexpr int s_lo = CH * SC_;
  constexpr int s_hi = s_lo + SC_;
  const int tid = threadIdx.x;
  const int p   = pc * 256 + tid;
  const bool act = (p < P_);

  if (tid < 50) {
    sm.outr.W2s[tid] = W2[tid];
    sm.outr.tgt[tid] = tgt[b * T_ + tid];
  }
  __syncthreads();

  // cosX gathers: input data, no producer dependency -> issue first.
  float av[T_ - s_lo];
#pragma unroll
  for (int t = s_lo; t < T_; ++t)
    av[t - s_lo] = act ? cosX[sm.outr.tgt[t] * P_ + p] : 0.f;

  // Wait for the 64 XWT quads covering this p-chunk.
  if (tid < 64) {
    const int q = pc * 64 + tid;
    if (q < NQ_) wait_flag(&quadflag[q]);
  }
  __syncthreads();

  v2f S2[25];
#pragma unroll
  for (int jj = 0; jj < 25; ++jj) {
    v2f t2;
    t2.x = act ? ld_coh(&XWT[(2 * jj) * P_ + p]) : 0.f;
    t2.y = act ? ld_coh(&XWT[(2 * jj + 1) * P_ + p]) : 0.f;
    S2[jj] = t2;
  }

  if (tid == 0) wait_flag(&gflag[b]);
  __syncthreads();
  for (int i = s_lo * 50 + tid; i < T_ * 50; i += 256)
    sm.outr.G[i] = ld_coh(&G[b * T_ * 50 + i]);
  __syncthreads();

  // Suffix prefix: t = T-1 down to s_hi — same fma order as verified kernel.
#pragma unroll
  for (int t = T_ - 1; t >= s_hi; --t) {
    const v2f* G2 = (const v2f*)&sm.outr.G[t * 50];
    v2f av2; av2.x = av[t - s_lo]; av2.y = av[t - s_lo];
#pragma unroll
    for (int jj = 0; jj < 25; ++jj)
      S2[jj] = __builtin_elementwise_fma(av2, G2[jj], S2[jj]);
  }

  const v2f* W2_2 = (const v2f*)sm.outr.W2s;
  const float b2v = b2[0];
  const v2f zero2 = {0.f, 0.f};
#pragma unroll
  for (int s = s_hi - 1; s >= s_lo; --s) {
    const v2f* G2 = (const v2f*)&sm.outr.G[s * 50];
    v2f av2; av2.x = av[s - s_lo]; av2.y = av[s - s_lo];
    v2f acc2; acc2.x = b2v; acc2.y = 0.f;
#pragma unroll
    for (int jj = 0; jj < 25; ++jj) {
      S2[jj] = __builtin_elementwise_fma(av2, G2[jj], S2[jj]);
      const v2f r = __builtin_elementwise_max(S2[jj], zero2);
      acc2 = __builtin_elementwise_fma(r, W2_2[jj], acc2);
    }
    if (act) out[(b * T_ + s) * P_ + p] = acc2.x + acc2.y;
  }
}

// ---------------------------------------------------------------------------
// Single fused kernel: 456 blocks. LDS 64.25 KB/block -> 2 blocks/CU; 512
// resident slots >= 456 blocks, so full co-residency (deadlock-freedom)
// holds regardless of dispatch order. Every awaited flag has an
// unconditional producer.
// ---------------------------------------------------------------------------
__global__ __launch_bounds__(256) void mega_kernel(
    const int* __restrict__ tgt, const int* __restrict__ cor,
    const float* __restrict__ X, const float* __restrict__ cosX,
    const float* __restrict__ emb2, const float* __restrict__ Wk,
    const float* __restrict__ Wr, const float* __restrict__ bl,
    const float* __restrict__ W1, const float* __restrict__ b1,
    const float* __restrict__ W2, const float* __restrict__ b2,
    float* __restrict__ ZX, float* __restrict__ G, float* __restrict__ XWT,
    int* __restrict__ zxflag, int* __restrict__ gflag,
    int* __restrict__ quadflag, float* __restrict__ out) {
  __shared__ __align__(16) SMem sm;
  const int blk = blockIdx.x;

  if (blk < B_) {
    lstm_role(blk, sm, ZX, Wr, bl, W1, G, zxflag, gflag);
    return;
  }
  if (blk < OUT_BASE_) {
    prod_role(blk, sm, tgt, cor, X, emb2, Wk, W1, b1, ZX, XWT, zxflag, quadflag);
    return;
  }
  const int obi = blk - OUT_BASE_;
  const int pc  = obi % 20;
  const int b   = (obi / 20) & 1;
  switch (obi / 40) {
    case 0: out_body<0>(pc, b, sm, tgt, cosX, G, XWT, W2, b2, out, gflag, quadflag); break;
    case 1: out_body<1>(pc, b, sm, tgt, cosX, G, XWT, W2, b2, out, gflag, quadflag); break;
    case 2: out_body<2>(pc, b, sm, tgt, cosX, G, XWT, W2, b2, out, gflag, quadflag); break;
    case 3: out_body<3>(pc, b, sm, tgt, cosX, G, XWT, W2, b2, out, gflag, quadflag); break;
    default: out_body<4>(pc, b, sm, tgt, cosX, G, XWT, W2, b2, out, gflag, quadflag); break;
  }
}

extern "C" void kernel_launch(void* const* d_in, const int* in_sizes, int n_in,
                              void* d_out, int out_size, void* d_ws, size_t ws_size,
                              hipStream_t stream) {
  const int*   tgt  = (const int*)d_in[0];
  const int*   cor  = (const int*)d_in[1];
  const float* X    = (const float*)d_in[3];
  const float* cosX = (const float*)d_in[4];
  const float* emb2 = (const float*)d_in[6];
  const float* Wk   = (const float*)d_in[7];
  const float* Wr   = (const float*)d_in[8];
  const float* bl   = (const float*)d_in[9];
  const float* W1   = (const float*)d_in[10];
  const float* b1   = (const float*)d_in[11];
  const float* W2   = (const float*)d_in[12];
  const float* b2   = (const float*)d_in[13];
  float* out = (float*)d_out;

  float* ws  = (float*)d_ws;
  float* ZX  = ws;            // 100*256 = 25600 floats
  float* G   = ws + 25600;    // 100*50  =  5000 floats
  float* XWT = ws + 30600;    // 50*5111 = 255550 floats
  int*   fl  = (int*)(ws + 286150);
  int* zxflag   = fl;         // 100
  int* gflag    = fl + 100;   // 2
  int* quadflag = fl + 102;   // 1278

  mega_kernel<<<dim3(GRID_), dim3(256), 0, stream>>>(
      tgt, cor, X, cosX, emb2, Wk, Wr, bl, W1, b1, W2, b2,
      ZX, G, XWT, zxflag, gflag, quadflag, out);
}